// Round 5
// baseline (351.283 us; speedup 1.0000x reference)
//
#include <hip/hip_runtime.h>
#include <hip/hip_bf16.h>

// Problem constants: B=2, S=2048, HID=2048, H=16, HD=128, HD2=64, LAT=256
#define BB 2
#define SS 2048
#define HID 2048
#define NH 16
#define BS (BB*SS)          // 4096 rows
#define SCALE 0.088388347648318447f   // 1/sqrt(128)
#define C2LOG 0.12751743f              // SCALE * log2(e)

typedef __bf16 bf16x8 __attribute__((ext_vector_type(8)));
typedef float f32x4 __attribute__((ext_vector_type(4)));
typedef float f32x16 __attribute__((ext_vector_type(16)));
typedef unsigned int uintx2 __attribute__((ext_vector_type(2)));

__device__ __forceinline__ bf16x8 ld_frag(const __hip_bfloat16* p) {
    uint4 u = *reinterpret_cast<const uint4*>(p);
    return __builtin_bit_cast(bf16x8, u);
}
__device__ __forceinline__ void store_c(__hip_bfloat16* C, size_t idx, float v) {
    C[idx] = __float2bfloat16(v);
}
__device__ __forceinline__ void store_c(float* C, size_t idx, float v) {
    C[idx] = v;
}
__device__ __forceinline__ ushort bf_bits(float v) {
    __hip_bfloat16 h = __float2bfloat16(v);
    return *reinterpret_cast<ushort*>(&h);
}

// async global->LDS, 16B per lane; lds addr must be wave-uniform base + lane*16
#define GLD16(gp, lp) \
  __builtin_amdgcn_global_load_lds((const __attribute__((address_space(1))) void*)(gp), \
                                   (__attribute__((address_space(3))) void*)(lp), 16, 0, 0)

// ---------------------------------------------------------------------------
// fp32 -> bf16 flat convert (hs)
// ---------------------------------------------------------------------------
__global__ __launch_bounds__(256) void convert_kernel(
    const float* __restrict__ src, __hip_bfloat16* __restrict__ dst, int n8)
{
    int i = blockIdx.x * blockDim.x + threadIdx.x;
    if (i >= n8) return;
    float4 a = reinterpret_cast<const float4*>(src)[2 * i];
    float4 b = reinterpret_cast<const float4*>(src)[2 * i + 1];
    ushort u[8] = { bf_bits(a.x), bf_bits(a.y), bf_bits(a.z), bf_bits(a.w),
                    bf_bits(b.x), bf_bits(b.y), bf_bits(b.z), bf_bits(b.w) };
    reinterpret_cast<uint4*>(dst)[i] = *reinterpret_cast<uint4*>(u);
}

// ---------------------------------------------------------------------------
// Fused weight transpose+convert: 8 segments, src fp32 [R][C] -> dst bf16 [C][R]
// ---------------------------------------------------------------------------
__global__ __launch_bounds__(256) void transpose_weights_kernel(
    const float* s0, const float* s1, const float* s2, const float* s3,
    const float* s4, const float* s5, const float* s6, const float* s7,
    __hip_bfloat16* WT1, __hip_bfloat16* WT2, __hip_bfloat16* WT3,
    __hip_bfloat16* WTo)
{
    const float* srcs[8] = { s0, s1, s2, s3, s4, s5, s6, s7 };
    const int Rs[8] = { 2048, 2048, 2048, 256, 256, 256, 256, 2048 };
    const int Cs[8] = { 256, 256, 1024, 1024, 2048, 1024, 1024, 2048 };
    __hip_bfloat16* dsts[8] = {
        WT1, WT1 + (size_t)256 * 2048, WT1 + (size_t)512 * 2048,
        WT2, WT2 + (size_t)1024 * 256,
        WT3, WT3 + (size_t)1024 * 256,
        WTo };
    const int prefix[9] = { 0, 512, 1024, 3072, 3328, 3840, 4096, 4352, 8448 };

    int bid = blockIdx.x;
    int seg = 0;
    #pragma unroll
    for (int i = 0; i < 8; i++) if (bid >= prefix[i + 1]) seg = i + 1;
    int local = bid - prefix[seg];
    int R = Rs[seg], C = Cs[seg];
    int tilesC = C / 32;
    int tr = local / tilesC, tc = local % tilesC;
    int r0 = tr * 32, c0 = tc * 32;
    const float* src = srcs[seg];
    __hip_bfloat16* dst = dsts[seg];

    __shared__ float Ts[32][33];
    int t = threadIdx.x;
    int ty = t >> 5, tx = t & 31;
    #pragma unroll
    for (int k = 0; k < 4; k++) {
        int r = ty + k * 8;
        Ts[r][tx] = src[(size_t)(r0 + r) * C + c0 + tx];
    }
    __syncthreads();
    #pragma unroll
    for (int k = 0; k < 4; k++) {
        int r = ty + k * 8;
        dst[(size_t)(c0 + r) * R + r0 + tx] = __float2bfloat16(Ts[tx][r]);
    }
}

// ---------------------------------------------------------------------------
// m97-style GEMM: C = A[M,K] * Bt[N,K]^T, bf16 in, fp32 acc.
// 128x128 tile, BK=32, global_load_lds staging, 4 waves each 64x64.
// r4: + bijective XCD swizzle (T1, m204 form; all our grids have nwg%8==0)
// so consecutive work items (sharing B-panels) land on the same XCD's L2.
// Epilogue routing: col < splitN -> (C0,...) else (C1,...). cm = output scale.
//   s64==0: plain col;  s64==1: col c -> (c>>6)*128 + (c&63) + off (head scatter)
//   s64==2: transposed store: Cp[(size_t)c*4096 + row]  (V-transpose for flash)
// ---------------------------------------------------------------------------
template <typename TC>
__global__ __launch_bounds__(256) void gemm_bt_kernel(
    const __hip_bfloat16* __restrict__ A, int lda,
    const __hip_bfloat16* __restrict__ Bt,
    TC* __restrict__ C0, int ldc0, int sp0, int off0, float cm0,
    TC* __restrict__ C1, int ldc1, int sp1, int off1, float cm1,
    int splitN, int K)
{
    __shared__ alignas(16) __hip_bfloat16 As[128 * 32];
    __shared__ alignas(16) __hip_bfloat16 Bs[128 * 32];

    // XCD-aware bijective remap (nwg % 8 == 0 for all launches here)
    const int nwg = gridDim.x * gridDim.y;
    int lin = blockIdx.y * gridDim.x + blockIdx.x;
    lin = (lin & 7) * (nwg >> 3) + (lin >> 3);
    const int bn = (lin % gridDim.x) * 128;
    const int bm = (lin / gridDim.x) * 128;

    const int t = threadIdx.x;
    const int w = t >> 6;
    const int lane = t & 63;
    const int l15 = lane & 15;
    const int quad = lane >> 4;
    const int wm = (w & 1) * 64;
    const int wn = (w >> 1) * 64;

    const int srow = lane >> 2;          // 0..15
    const int skcol = (lane & 3) * 8;    // 0,8,16,24

    f32x4 acc[4][4] = {};

    for (int k0 = 0; k0 < K; k0 += 32) {
        __syncthreads();
        #pragma unroll
        for (int i = 0; i < 2; i++) {
            int r = w * 32 + i * 16 + srow;
            GLD16(A + (size_t)(bm + r) * lda + k0 + skcol, &As[r * 32 + skcol]);
            GLD16(Bt + (size_t)(bn + r) * K + k0 + skcol, &Bs[r * 32 + skcol]);
        }
        __syncthreads();

        bf16x8 af[4], bf[4];
        #pragma unroll
        for (int mt = 0; mt < 4; mt++)
            af[mt] = ld_frag(&As[(wm + mt * 16 + l15) * 32 + quad * 8]);
        #pragma unroll
        for (int nt = 0; nt < 4; nt++)
            bf[nt] = ld_frag(&Bs[(wn + nt * 16 + l15) * 32 + quad * 8]);
        #pragma unroll
        for (int mt = 0; mt < 4; mt++)
            #pragma unroll
            for (int nt = 0; nt < 4; nt++)
                acc[mt][nt] = __builtin_amdgcn_mfma_f32_16x16x32_bf16(
                    af[mt], bf[nt], acc[mt][nt], 0, 0, 0);
    }

    #pragma unroll
    for (int nt = 0; nt < 4; nt++) {
        int col = bn + wn + nt * 16 + l15;
        TC* Cp; int c, ld, s64, off; float cm;
        if (col < splitN) { Cp = C0; c = col; ld = ldc0; s64 = sp0; off = off0; cm = cm0; }
        else { Cp = C1; c = col - splitN; ld = ldc1; s64 = sp1; off = off1; cm = cm1; }
        if (s64 == 2) {
            #pragma unroll
            for (int mt = 0; mt < 4; mt++) {
                int row0 = bm + wm + mt * 16 + quad * 4;
                #pragma unroll
                for (int r = 0; r < 4; r++)
                    store_c(Cp, (size_t)c * 4096 + row0 + r, acc[mt][nt][r] * cm);
            }
        } else {
            int oc = s64 ? ((c >> 6) * 128 + (c & 63) + off) : c;
            #pragma unroll
            for (int mt = 0; mt < 4; mt++) {
                #pragma unroll
                for (int r = 0; r < 4; r++) {
                    int row = bm + wm + mt * 16 + quad * 4 + r;
                    store_c(Cp, (size_t)row * ld + oc, acc[mt][nt][r] * cm);
                }
            }
        }
    }
}

// ---------------------------------------------------------------------------
// RoPE in-place on K/Q rope halves: cols h*128+64+i and h*128+96+i rotated.
// ---------------------------------------------------------------------------
__global__ __launch_bounds__(256) void rope_kernel(
    __hip_bfloat16* __restrict__ Kb, __hip_bfloat16* __restrict__ Qb)
{
    int idx = blockIdx.x * blockDim.x + threadIdx.x;
    if (idx >= BS * NH * 32) return;
    int i = idx & 31;
    int h = (idx >> 5) & 15;
    int row = idx >> 9;
    int s = row & (SS - 1);

    float inv = exp2f(-(float)i * 0.4152410118609203f);  // 10000^(-i/32)
    float ang = (float)s * inv;
    float sn = sinf(ang), cs = cosf(ang);

    size_t obase = (size_t)row * 2048 + h * 128 + 64 + i;
    {
        float x1 = __bfloat162float(Kb[obase]);
        float x2 = __bfloat162float(Kb[obase + 32]);
        Kb[obase]      = __float2bfloat16(x1 * cs - x2 * sn);
        Kb[obase + 32] = __float2bfloat16(x1 * sn + x2 * cs);
    }
    {
        float x1 = __bfloat162float(Qb[obase]);
        float x2 = __bfloat162float(Qb[obase + 32]);
        Qb[obase]      = __float2bfloat16(x1 * cs - x2 * sn);
        Qb[obase + 32] = __float2bfloat16(x1 * sn + x2 * cs);
    }
}

// ---------------------------------------------------------------------------
// Flash attention v12 = v11 pipeline + FRAGMENT-ORDER LDS layout.
// r4 evidence: 4.33M bank-conflict cycles; kf/vf reads (32 rows x 64B with
// 2-bit XOR swizzle) are structurally 4-way conflicted (64 lanes -> 8 slots),
// and swizzled addressing costs VALU. LDS read volume (256KB/CU/iter) is the
// binding resource.
// v12: K/V stored as 16 regions x 1KB per tile, region (s,kb)/(s,dt) = one
// MFMA fragment, slot l = exactly what lane l needs:
//   K region (kb,s) slot l = K[kv=kb*32+(l&31)][d=s*16+(l>>5)*8 ..+8]
//   V region (dt,s) slot l = Vt[d=dt*32+(l&31)][kv=s*16+(l>>5)*8 ..+8]
// Every ds_read_b128 is then wave-uniform base + lane*16 (canonical
// conflict-free, single vaddr + immediate offsets). Staging keeps GLD16's
// required linear dest and pre-swizzles the GLOBAL source per-lane
// (m173 / rule #21). Same traffic, same 4 GLD16/wave/tile, same vmcnt(4).
// ---------------------------------------------------------------------------
__global__ __launch_bounds__(512) void flash_attn_kernel(
    const __hip_bfloat16* __restrict__ Q,
    const __hip_bfloat16* __restrict__ Kb,
    const __hip_bfloat16* __restrict__ Vt,
    __hip_bfloat16* __restrict__ O)
{
    __shared__ alignas(16) __hip_bfloat16 Ktd[2 * 16 * 512];  // [par][region kb*8+s][slot]
    __shared__ alignas(16) __hip_bfloat16 Vsd[2 * 16 * 512];  // [par][region dt*4+s][slot]

    const int p = blockIdx.x;            // pair index 0..7
    const int h = blockIdx.y;
    const int b = blockIdx.z;
    const int t = threadIdx.x;
    const int w = t >> 6;                // 0..7
    const int lane = t & 63;
    const int l31 = lane & 31;
    const int hi = lane >> 5;

    const int qt = (w < 4) ? (15 - p) : p;   // this wave's q-tile
    const int wq = w & 3;
    const int qwb = qt * 128 + wq * 32;      // wave's q base (32 rows)
    const int q = qwb + l31;                 // this lane's q row
    const int my_nt = 2 * qt + 1 + (wq >> 1);// kv tiles this wave needs
    const int nbig = 2 * (15 - p) + 2;       // shared loop length

    const __hip_bfloat16* Kbase = Kb + (size_t)(b * SS) * 2048 + h * 128;
    const __hip_bfloat16* Vtb = Vt + (size_t)(h * 128) * 4096 + b * SS;

    // Q B-frags: qf[s] = Q[q][d = 16s + 8hi + j], j=0..7
    bf16x8 qf[8];
    {
        const __hip_bfloat16* qrow = Q + (size_t)(b * SS + q) * 2048 + h * 128;
        #pragma unroll
        for (int s = 0; s < 8; s++)
            qf[s] = ld_frag(qrow + s * 16 + hi * 8);
    }

    // staging assignment: wave w stages K regions {2w, 2w+1} and V regions
    // {2w, 2w+1}. K region r=(kb*8+s): kb=w>>2, s=(2w&7)+i.
    //             V region r=(dt*4+s): dt=w>>1, s=(2w&3)+i.
    const int kb_w = w >> 2, ks0 = (2 * w) & 7;
    const int dt_w = w >> 1, vs0 = (2 * w) & 3;
    // per-lane global offsets (element units), constant across tiles:
    //   K: row l31, d-offset = s*16 + hi*8 (s varies per issue)
    const size_t kg_l = (size_t)l31 * 2048 + hi * 8;
    const size_t vg_l = (size_t)(dt_w * 32 + l31) * 4096 + hi * 8;
    const int loff = lane * 8;               // LDS slot offset (elements)

    float m_i = -INFINITY;   // running max, log2 domain (S * C2LOG)
    float l_i = 0.0f;
    f32x16 acc[4] = {};      // O^T: acc[dt], d = dt*32 + 8*(e>>2) + 4hi + (e&3), col q=l31

    // prologue: stage tile 0 (K and V) into par 0
    #pragma unroll
    for (int i = 0; i < 2; i++)
        GLD16(Kbase + (size_t)(kb_w * 32) * 2048 + kg_l + (ks0 + i) * 16,
              &Ktd[(kb_w * 8 + ks0 + i) * 512 + loff]);
    #pragma unroll
    for (int i = 0; i < 2; i++)
        GLD16(Vtb + vg_l + (vs0 + i) * 16,
              &Vsd[(dt_w * 4 + vs0 + i) * 512 + loff]);
    // pin the qf waitcnt into the prologue (fake use)
    asm volatile("" :: "v"(qf[0]), "v"(qf[1]), "v"(qf[2]), "v"(qf[3]),
                       "v"(qf[4]), "v"(qf[5]), "v"(qf[6]), "v"(qf[7]));

    for (int kt = 0; kt < nbig; kt++) {
        const int kvb = kt * 64;
        const int par = kt & 1;
        const bool active = (kt < my_nt);

        __builtin_amdgcn_s_barrier();              // A: all waves done reading buf[par^1]
        asm volatile("" ::: "memory");

        // ---- prefetch tile kt+1 into buf[par^1] (clamped dup on last) ----
        {
            const int kvb1 = ((kt + 1 < nbig) ? kt + 1 : kt) * 64;
            const int pn = (par ^ 1) * 8192;
            #pragma unroll
            for (int i = 0; i < 2; i++)
                GLD16(Kbase + (size_t)(kvb1 + kb_w * 32) * 2048 + kg_l + (ks0 + i) * 16,
                      &Ktd[pn + (kb_w * 8 + ks0 + i) * 512 + loff]);
            #pragma unroll
            for (int i = 0; i < 2; i++)
                GLD16(Vtb + vg_l + kvb1 + (vs0 + i) * 16,
                      &Vsd[pn + (dt_w * 4 + vs0 + i) * 512 + loff]);
        }
        asm volatile("s_waitcnt vmcnt(4)" ::: "memory");  // tile kt landed (own 4)
        __builtin_amdgcn_s_barrier();              // B: tile kt visible block-wide
        asm volatile("" ::: "memory");

        if (active) {
            const __hip_bfloat16* kb_base = &Ktd[par * 8192];
            const __hip_bfloat16* vb_base = &Vsd[par * 8192];

            // ---- S^T = K * Q^T : 2 kv-blocks x 8 k-steps of 32x32x16 ----
            f32x16 st[2] = {};
            __builtin_amdgcn_s_setprio(1);
            #pragma unroll
            for (int s = 0; s < 8; s++)
                #pragma unroll
                for (int kb = 0; kb < 2; kb++) {
                    bf16x8 kf = ld_frag(kb_base + (kb * 8 + s) * 512 + loff);
                    st[kb] = __builtin_amdgcn_mfma_f32_32x32x16_bf16(
                        kf, qf[s], st[kb], 0, 0, 0);
                }
            __builtin_amdgcn_s_setprio(0);

            // ---- row max; causal cndmask only on the diagonal tile ----
            float tmx = -INFINITY;
            if (kvb + 63 > qwb) {            // wave-uniform: diagonal tile
                const int thr = q - kvb - 4 * hi;   // pass iff kb*32 + 8g + r <= thr
                #pragma unroll
                for (int kb = 0; kb < 2; kb++)
                    #pragma unroll
                    for (int g = 0; g < 4; g++)
                        #pragma unroll
                        for (int r = 0; r < 4; r++) {
                            const int e = g * 4 + r;
                            float v = (kb * 32 + 8 * g + r <= thr) ? st[kb][e] : -INFINITY;
                            st[kb][e] = v;
                            tmx = fmaxf(tmx, v);
                        }
            } else {                          // interior: no masking needed
                #pragma unroll
                for (int kb = 0; kb < 2; kb++)
                    #pragma unroll
                    for (int e = 0; e < 16; e++)
                        tmx = fmaxf(tmx, st[kb][e]);
            }
            tmx = fmaxf(tmx, __shfl_xor(tmx, 32));
            const float m2x = tmx * C2LOG;

            // ---- online softmax (log2 domain) + T13 defer-max ----
            const bool nosc = __all(m2x <= m_i + 8.0f);
            const float mnew = nosc ? m_i : fmaxf(m_i, m2x);
            float rs = 0.0f;
            #pragma unroll
            for (int kb = 0; kb < 2; kb++)
                #pragma unroll
                for (int e = 0; e < 16; e++) {
                    float pv = exp2f(fmaf(st[kb][e], C2LOG, -mnew));
                    st[kb][e] = pv;
                    rs += pv;
                }
            rs += __shfl_xor(rs, 32);
            if (!nosc) {
                const float alpha = exp2f(m_i - mnew);
                m_i = mnew;
                l_i *= alpha;
                #pragma unroll
                for (int dt = 0; dt < 4; dt++)
                    #pragma unroll
                    for (int e = 0; e < 16; e++)
                        acc[dt][e] *= alpha;
            }
            l_i += rs;

            // ---- P -> bf16 PV B-frags entirely in registers (T12) ----
            uint4 af[4];
            #pragma unroll
            for (int kb = 0; kb < 2; kb++) {
                unsigned int pk[4][2];
                #pragma unroll
                for (int g = 0; g < 4; g++)
                    #pragma unroll
                    for (int i = 0; i < 2; i++) {
                        float2 fp = make_float2(st[kb][g * 4 + 2 * i],
                                                st[kb][g * 4 + 2 * i + 1]);
                        __hip_bfloat162 h2 = __float22bfloat162_rn(fp);
                        pk[g][i] = *reinterpret_cast<unsigned int*>(&h2);
                    }
                #pragma unroll
                for (int sl = 0; sl < 2; sl++) {
                    uintx2 r0 = __builtin_amdgcn_permlane32_swap(
                        pk[2 * sl][0], pk[2 * sl + 1][0], false, false);
                    uintx2 r1 = __builtin_amdgcn_permlane32_swap(
                        pk[2 * sl][1], pk[2 * sl + 1][1], false, false);
                    af[kb * 2 + sl] = make_uint4(r0[0], r1[0], r0[1], r1[1]);
                }
            }

            // ---- O^T += V^T * P^T : 4 d-tiles x 4 kv-steps ----
            __builtin_amdgcn_s_setprio(1);
            #pragma unroll
            for (int s = 0; s < 4; s++) {
                bf16x8 pf = __builtin_bit_cast(bf16x8, af[s]);
                #pragma unroll
                for (int dt = 0; dt < 4; dt++) {
                    bf16x8 vf = ld_frag(vb_base + (dt * 4 + s) * 512 + loff);
                    acc[dt] = __builtin_amdgcn_mfma_f32_32x32x16_bf16(
                        vf, pf, acc[dt], 0, 0, 0);
                }
            }
            __builtin_amdgcn_s_setprio(0);
        }
    }

    // ---- epilogue: per-lane q = l31, d = dt*32 + 8g + 4hi + r ----
    const float inv_l = 1.0f / l_i;
    __hip_bfloat16* orow = O + (size_t)(b * SS + q) * 2048 + h * 128;
    #pragma unroll
    for (int dt = 0; dt < 4; dt++)
        #pragma unroll
        for (int g = 0; g < 4; g++) {
            ushort u[4];
            #pragma unroll
            for (int r = 0; r < 4; r++)
                u[r] = bf_bits(acc[dt][g * 4 + r] * inv_l);
            *reinterpret_cast<uint2*>(orow + dt * 32 + 8 * g + 4 * hi) =
                *reinterpret_cast<uint2*>(u);
        }
}

// ---------------------------------------------------------------------------
extern "C" void kernel_launch(void* const* d_in, const int* in_sizes, int n_in,
                              void* d_out, int out_size, void* d_ws, size_t ws_size,
                              hipStream_t stream)
{
    const float* hs       = (const float*)d_in[0];
    const float* w_kv_d   = (const float*)d_in[1];
    const float* w_q_d    = (const float*)d_in[2];
    const float* w_k_u    = (const float*)d_in[3];
    const float* w_q_u    = (const float*)d_in[4];
    const float* w_v_u    = (const float*)d_in[5];
    const float* w_rope_k = (const float*)d_in[6];
    const float* w_rope_q = (const float*)d_in[7];
    const float* w_o      = (const float*)d_in[8];
    float* out = (float*)d_out;

    char* p = (char*)d_ws;
    auto alloc = [&](size_t nelem) {
        __hip_bfloat16* r = (__hip_bfloat16*)p;
        p += nelem * sizeof(__hip_bfloat16);
        return r;
    };
    __hip_bfloat16* hsb  = alloc((size_t)BS * HID);        // 16 MB (reused as attn)
    __hip_bfloat16* qkvd = alloc((size_t)BS * 512);        // 4 MB
    __hip_bfloat16* WT1  = alloc((size_t)1536 * 2048);     // 6 MB
    __hip_bfloat16* WT2  = alloc((size_t)3072 * 256);      // 1.5 MB
    __hip_bfloat16* WT3  = alloc((size_t)2048 * 256);      // 1 MB
    __hip_bfloat16* WTo  = alloc((size_t)2048 * 2048);     // 8 MB
    __hip_bfloat16* Kbuf = alloc((size_t)BS * HID);        // 16 MB
    __hip_bfloat16* Qbuf = alloc((size_t)BS * HID);        // 16 MB
    __hip_bfloat16* Vtb  = alloc((size_t)HID * BS);        // 16 MB, [h*128+d][b*S+s]
    __hip_bfloat16* attn = hsb;   // hs dead after G1

    dim3 blk(256);

    // 0a. hs -> bf16
    convert_kernel<<<dim3((BS * HID / 8 + 255) / 256), blk, 0, stream>>>(
        hs, hsb, BS * HID / 8);
    // 0b. all weights: transpose + convert to bf16 W^T
    transpose_weights_kernel<<<dim3(8448), blk, 0, stream>>>(
        w_kv_d, w_q_d, w_rope_k, w_k_u, w_v_u, w_q_u, w_rope_q, w_o,
        WT1, WT2, WT3, WTo);

    // G1: [kv_d | q_d | krp] = hsb @ WT1^T  (N=1536, K=2048)
    gemm_bt_kernel<__hip_bfloat16><<<dim3(1536 / 128, BS / 128), blk, 0, stream>>>(
        hsb, 2048, WT1,
        qkvd, 512, 0, 0, 1.0f,
        Kbuf, 2048, 1, 64, 1.0f,
        512, 2048);
    // G2: [k_p | v] = kv_d @ WT2^T  (N=3072, K=256)
    gemm_bt_kernel<__hip_bfloat16><<<dim3(3072 / 128, BS / 128), blk, 0, stream>>>(
        qkvd, 512, WT2,
        Kbuf, 2048, 1, 0, 1.0f,
        Vtb, 0, 2, 0, 1.0f,
        1024, 256);
    // G3: [q_p | q_rope_pre] = q_d @ WT3^T  (N=2048, K=256)
    gemm_bt_kernel<__hip_bfloat16><<<dim3(2048 / 128, BS / 128), blk, 0, stream>>>(
        qkvd + 256, 512, WT3,
        Qbuf, 2048, 1, 0, 1.0f,
        Qbuf, 2048, 1, 64, 1.0f,
        1024, 256);
    // 4. RoPE in-place on K/Q rope halves
    rope_kernel<<<dim3((BS * NH * 32 + 255) / 256), blk, 0, stream>>>(Kbuf, Qbuf);
    // 5. flash attention v12 -> attn (fragment-order LDS, conflict-free reads)
    flash_attn_kernel<<<dim3(8, NH, BB), dim3(512), 0, stream>>>(
        Qbuf, Kbuf, Vtb, attn);
    // G4: out = attn @ WTo^T (fp32 out)
    gemm_bt_kernel<float><<<dim3(2048 / 128, BS / 128), blk, 0, stream>>>(
        attn, 2048, WTo,
        out, 2048, 0, 0, 1.0f,
        out, 2048, 0, 0, 1.0f,
        2048, 2048);
}

// Round 6
// 345.592 us; speedup vs baseline: 1.0165x; 1.0165x over previous
//
#include <hip/hip_runtime.h>
#include <hip/hip_bf16.h>

// Problem constants: B=2, S=2048, HID=2048, H=16, HD=128, HD2=64, LAT=256
#define BB 2
#define SS 2048
#define HID 2048
#define NH 16
#define BS (BB*SS)          // 4096 rows
#define SCALE 0.088388347648318447f   // 1/sqrt(128)
#define C2LOG 0.12751743f              // SCALE * log2(e)

typedef __bf16 bf16x8 __attribute__((ext_vector_type(8)));
typedef float f32x4 __attribute__((ext_vector_type(4)));
typedef float f32x16 __attribute__((ext_vector_type(16)));
typedef unsigned int uintx2 __attribute__((ext_vector_type(2)));

__device__ __forceinline__ bf16x8 ld_frag(const __hip_bfloat16* p) {
    uint4 u = *reinterpret_cast<const uint4*>(p);
    return __builtin_bit_cast(bf16x8, u);
}
__device__ __forceinline__ void store_c(__hip_bfloat16* C, size_t idx, float v) {
    C[idx] = __float2bfloat16(v);
}
__device__ __forceinline__ void store_c(float* C, size_t idx, float v) {
    C[idx] = v;
}
__device__ __forceinline__ ushort bf_bits(float v) {
    __hip_bfloat16 h = __float2bfloat16(v);
    return *reinterpret_cast<ushort*>(&h);
}

// async global->LDS, 16B per lane; lds addr must be wave-uniform base + lane*16
#define GLD16(gp, lp) \
  __builtin_amdgcn_global_load_lds((const __attribute__((address_space(1))) void*)(gp), \
                                   (__attribute__((address_space(3))) void*)(lp), 16, 0, 0)

// ---------------------------------------------------------------------------
// Fragment-order global layouts (v13).
// Kf: element K[b][kv][h][d] ->
//   (b*16+h)*262144 + (kv>>5)*4096 + (d>>4)*512 + ((d>>3)&1)*256 + (kv&31)*8 + (d&7)
// Vf: element V[b][kv][h][d] ->
//   (b*16+h)*262144 + (kv>>6)*8192 + (d>>5)*2048 + ((kv>>4)&3)*512
//   + ((kv>>3)&1)*256 + (d&31)*8 + (kv&7)
// Each 512-element (1KB) region is exactly one 32x32x16 MFMA A-operand
// fragment: slot l = what lane l needs (validated on-device by v12's LDS
// arrangement, which is identical).
// ---------------------------------------------------------------------------

// ---------------------------------------------------------------------------
// fp32 -> bf16 flat convert (hs)
// ---------------------------------------------------------------------------
__global__ __launch_bounds__(256) void convert_kernel(
    const float* __restrict__ src, __hip_bfloat16* __restrict__ dst, int n8)
{
    int i = blockIdx.x * blockDim.x + threadIdx.x;
    if (i >= n8) return;
    float4 a = reinterpret_cast<const float4*>(src)[2 * i];
    float4 b = reinterpret_cast<const float4*>(src)[2 * i + 1];
    ushort u[8] = { bf_bits(a.x), bf_bits(a.y), bf_bits(a.z), bf_bits(a.w),
                    bf_bits(b.x), bf_bits(b.y), bf_bits(b.z), bf_bits(b.w) };
    reinterpret_cast<uint4*>(dst)[i] = *reinterpret_cast<uint4*>(u);
}

// ---------------------------------------------------------------------------
// Fused weight transpose+convert: 8 segments, src fp32 [R][C] -> dst bf16 [C][R]
// ---------------------------------------------------------------------------
__global__ __launch_bounds__(256) void transpose_weights_kernel(
    const float* s0, const float* s1, const float* s2, const float* s3,
    const float* s4, const float* s5, const float* s6, const float* s7,
    __hip_bfloat16* WT1, __hip_bfloat16* WT2, __hip_bfloat16* WT3,
    __hip_bfloat16* WTo)
{
    const float* srcs[8] = { s0, s1, s2, s3, s4, s5, s6, s7 };
    const int Rs[8] = { 2048, 2048, 2048, 256, 256, 256, 256, 2048 };
    const int Cs[8] = { 256, 256, 1024, 1024, 2048, 1024, 1024, 2048 };
    __hip_bfloat16* dsts[8] = {
        WT1, WT1 + (size_t)256 * 2048, WT1 + (size_t)512 * 2048,
        WT2, WT2 + (size_t)1024 * 256,
        WT3, WT3 + (size_t)1024 * 256,
        WTo };
    const int prefix[9] = { 0, 512, 1024, 3072, 3328, 3840, 4096, 4352, 8448 };

    int bid = blockIdx.x;
    int seg = 0;
    #pragma unroll
    for (int i = 0; i < 8; i++) if (bid >= prefix[i + 1]) seg = i + 1;
    int local = bid - prefix[seg];
    int R = Rs[seg], C = Cs[seg];
    int tilesC = C / 32;
    int tr = local / tilesC, tc = local % tilesC;
    int r0 = tr * 32, c0 = tc * 32;
    const float* src = srcs[seg];
    __hip_bfloat16* dst = dsts[seg];

    __shared__ float Ts[32][33];
    int t = threadIdx.x;
    int ty = t >> 5, tx = t & 31;
    #pragma unroll
    for (int k = 0; k < 4; k++) {
        int r = ty + k * 8;
        Ts[r][tx] = src[(size_t)(r0 + r) * C + c0 + tx];
    }
    __syncthreads();
    #pragma unroll
    for (int k = 0; k < 4; k++) {
        int r = ty + k * 8;
        dst[(size_t)(c0 + r) * R + r0 + tx] = __float2bfloat16(Ts[tx][r]);
    }
}

// ---------------------------------------------------------------------------
// m97-style GEMM: C = A[M,K] * Bt[N,K]^T, bf16 in, fp32 acc.
// 128x128 tile, BK=32, global_load_lds staging, 4 waves each 64x64.
// + bijective XCD swizzle (T1; all grids here have nwg%8==0).
// Epilogue routing: col < splitN -> (C0,...) else (C1,...). cm = output scale.
//   s64==0: plain col
//   s64==1: col c -> (c>>6)*128 + (c&63) + off (head scatter, row-major)
//   s64==2: transposed store: Cp[c*4096 + row]
//   s64==3: Kf fragment-order scatter; c: h=c>>6, d=off+(c&63); row m: b,kv
//   s64==4: Vf fragment-order scatter; c: h=c>>7, d=c&127;    row m: b,kv
// ---------------------------------------------------------------------------
template <typename TC>
__global__ __launch_bounds__(256) void gemm_bt_kernel(
    const __hip_bfloat16* __restrict__ A, int lda,
    const __hip_bfloat16* __restrict__ Bt,
    TC* __restrict__ C0, int ldc0, int sp0, int off0, float cm0,
    TC* __restrict__ C1, int ldc1, int sp1, int off1, float cm1,
    int splitN, int K)
{
    __shared__ alignas(16) __hip_bfloat16 As[128 * 32];
    __shared__ alignas(16) __hip_bfloat16 Bs[128 * 32];

    // XCD-aware bijective remap (nwg % 8 == 0 for all launches here)
    const int nwg = gridDim.x * gridDim.y;
    int lin = blockIdx.y * gridDim.x + blockIdx.x;
    lin = (lin & 7) * (nwg >> 3) + (lin >> 3);
    const int bn = (lin % gridDim.x) * 128;
    const int bm = (lin / gridDim.x) * 128;

    const int t = threadIdx.x;
    const int w = t >> 6;
    const int lane = t & 63;
    const int l15 = lane & 15;
    const int quad = lane >> 4;
    const int wm = (w & 1) * 64;
    const int wn = (w >> 1) * 64;

    const int srow = lane >> 2;          // 0..15
    const int skcol = (lane & 3) * 8;    // 0,8,16,24

    f32x4 acc[4][4] = {};

    for (int k0 = 0; k0 < K; k0 += 32) {
        __syncthreads();
        #pragma unroll
        for (int i = 0; i < 2; i++) {
            int r = w * 32 + i * 16 + srow;
            GLD16(A + (size_t)(bm + r) * lda + k0 + skcol, &As[r * 32 + skcol]);
            GLD16(Bt + (size_t)(bn + r) * K + k0 + skcol, &Bs[r * 32 + skcol]);
        }
        __syncthreads();

        bf16x8 af[4], bf[4];
        #pragma unroll
        for (int mt = 0; mt < 4; mt++)
            af[mt] = ld_frag(&As[(wm + mt * 16 + l15) * 32 + quad * 8]);
        #pragma unroll
        for (int nt = 0; nt < 4; nt++)
            bf[nt] = ld_frag(&Bs[(wn + nt * 16 + l15) * 32 + quad * 8]);
        #pragma unroll
        for (int mt = 0; mt < 4; mt++)
            #pragma unroll
            for (int nt = 0; nt < 4; nt++)
                acc[mt][nt] = __builtin_amdgcn_mfma_f32_16x16x32_bf16(
                    af[mt], bf[nt], acc[mt][nt], 0, 0, 0);
    }

    #pragma unroll
    for (int nt = 0; nt < 4; nt++) {
        int col = bn + wn + nt * 16 + l15;
        TC* Cp; int c, ld, s64, off; float cm;
        if (col < splitN) { Cp = C0; c = col; ld = ldc0; s64 = sp0; off = off0; cm = cm0; }
        else { Cp = C1; c = col - splitN; ld = ldc1; s64 = sp1; off = off1; cm = cm1; }
        if (s64 == 2) {
            #pragma unroll
            for (int mt = 0; mt < 4; mt++) {
                int row0 = bm + wm + mt * 16 + quad * 4;
                #pragma unroll
                for (int r = 0; r < 4; r++)
                    store_c(Cp, (size_t)c * 4096 + row0 + r, acc[mt][nt][r] * cm);
            }
        } else if (s64 == 3) {
            const int hh = c >> 6, d = off + (c & 63);
            const size_t dbase = (size_t)(d >> 4) * 512
                               + (size_t)((d >> 3) & 1) * 256 + (d & 7);
            #pragma unroll
            for (int mt = 0; mt < 4; mt++) {
                #pragma unroll
                for (int r = 0; r < 4; r++) {
                    int m = bm + wm + mt * 16 + quad * 4 + r;
                    int bb2 = m >> 11, kv = m & 2047;
                    size_t idx = (size_t)(bb2 * 16 + hh) * 262144
                               + (size_t)(kv >> 5) * 4096 + dbase
                               + (size_t)(kv & 31) * 8;
                    store_c(Cp, idx, acc[mt][nt][r] * cm);
                }
            }
        } else if (s64 == 4) {
            const int hh = c >> 7, d = c & 127;
            const size_t dbase = (size_t)(d >> 5) * 2048 + (size_t)(d & 31) * 8;
            #pragma unroll
            for (int mt = 0; mt < 4; mt++) {
                #pragma unroll
                for (int r = 0; r < 4; r++) {
                    int m = bm + wm + mt * 16 + quad * 4 + r;
                    int bb2 = m >> 11, kv = m & 2047;
                    size_t idx = (size_t)(bb2 * 16 + hh) * 262144
                               + (size_t)(kv >> 6) * 8192 + dbase
                               + (size_t)((kv >> 4) & 3) * 512
                               + (size_t)((kv >> 3) & 1) * 256 + (kv & 7);
                    store_c(Cp, idx, acc[mt][nt][r] * cm);
                }
            }
        } else {
            int oc = s64 ? ((c >> 6) * 128 + (c & 63) + off) : c;
            #pragma unroll
            for (int mt = 0; mt < 4; mt++) {
                #pragma unroll
                for (int r = 0; r < 4; r++) {
                    int row = bm + wm + mt * 16 + quad * 4 + r;
                    store_c(Cp, (size_t)row * ld + oc, acc[mt][nt][r] * cm);
                }
            }
        }
    }
}

// ---------------------------------------------------------------------------
// RoPE in-place: K in Kf fragment-order layout, Q in row-major Qbuf.
// Pair (d1=64+i, d2=96+i): in Kf, d2 is exactly +2 regions = +1024 elems.
// ---------------------------------------------------------------------------
__global__ __launch_bounds__(256) void rope_kernel(
    __hip_bfloat16* __restrict__ Kf, __hip_bfloat16* __restrict__ Qb)
{
    int idx = blockIdx.x * blockDim.x + threadIdx.x;
    if (idx >= BS * NH * 32) return;
    int i = idx & 31;
    int h = (idx >> 5) & 15;
    int row = idx >> 9;
    int s = row & (SS - 1);
    int b = row >> 11;

    float inv = exp2f(-(float)i * 0.4152410118609203f);  // 10000^(-i/32)
    float ang = (float)s * inv;
    float sn = sinf(ang), cs = cosf(ang);

    {   // K (Kf layout)
        size_t kaddr = ((size_t)(b * 16 + h) * 64 + (s >> 5)) * 4096
                     + (size_t)(4 + (i >> 4)) * 512
                     + (size_t)(((i >> 3) & 1) * 32 + (s & 31)) * 8 + (i & 7);
        float x1 = __bfloat162float(Kf[kaddr]);
        float x2 = __bfloat162float(Kf[kaddr + 1024]);
        Kf[kaddr]        = __float2bfloat16(x1 * cs - x2 * sn);
        Kf[kaddr + 1024] = __float2bfloat16(x1 * sn + x2 * cs);
    }
    {   // Q (row-major)
        size_t obase = (size_t)row * 2048 + h * 128 + 64 + i;
        float x1 = __bfloat162float(Qb[obase]);
        float x2 = __bfloat162float(Qb[obase + 32]);
        Qb[obase]      = __float2bfloat16(x1 * cs - x2 * sn);
        Qb[obase + 32] = __float2bfloat16(x1 * sn + x2 * cs);
    }
}

// ---------------------------------------------------------------------------
// Flash attention v13 = v12 compute core + fragment-order GLOBAL K/V.
// r5 post-mortem: v12's fragment-order LDS killed bank conflicts (4.33M->0)
// but its staging read 32 strided rows x 32B per GLD16 (vs v11's 16x64B)
// -> request-issue serialization cost 15us. Fix: producers (G1/G2/rope)
// write K/V in fragment order in GLOBAL memory, so staging is contiguous
// 1KB reads AND LDS reads stay conflict-free AND address math vanishes.
// Also: single barrier per iteration: {vmcnt(0) [loads a full compute-phase
// old]; s_barrier [=> all waves' tile-kt loads landed AND everyone done
// reading par^1]; stage kt+1 -> par^1; compute kt}.
// ---------------------------------------------------------------------------
__global__ __launch_bounds__(512) void flash_attn_kernel(
    const __hip_bfloat16* __restrict__ Q,
    const __hip_bfloat16* __restrict__ Kf,
    const __hip_bfloat16* __restrict__ Vf,
    __hip_bfloat16* __restrict__ O)
{
    __shared__ alignas(16) __hip_bfloat16 Ktd[2 * 16 * 512];  // [par][region kb*8+s][slot]
    __shared__ alignas(16) __hip_bfloat16 Vsd[2 * 16 * 512];  // [par][region dt*4+sr][slot]

    const int p = blockIdx.x;            // pair index 0..7
    const int h = blockIdx.y;
    const int b = blockIdx.z;
    const int t = threadIdx.x;
    const int w = t >> 6;                // 0..7
    const int lane = t & 63;
    const int l31 = lane & 31;
    const int hi = lane >> 5;

    const int qt = (w < 4) ? (15 - p) : p;   // this wave's q-tile
    const int wq = w & 3;
    const int qwb = qt * 128 + wq * 32;      // wave's q base (32 rows)
    const int q = qwb + l31;                 // this lane's q row
    const int my_nt = 2 * qt + 1 + (wq >> 1);// kv tiles this wave needs
    const int nbig = 2 * (15 - p) + 2;       // shared loop length

    const __hip_bfloat16* Kfb = Kf + (size_t)(b * 16 + h) * 262144;
    const __hip_bfloat16* Vfb = Vf + (size_t)(b * 16 + h) * 262144;

    // Q B-frags: qf[s] = Q[q][d = 16s + 8hi + j], j=0..7
    bf16x8 qf[8];
    {
        const __hip_bfloat16* qrow = Q + (size_t)(b * SS + q) * 2048 + h * 128;
        #pragma unroll
        for (int s = 0; s < 8; s++)
            qf[s] = ld_frag(qrow + s * 16 + hi * 8);
    }

    // staging assignment: wave w stages K regions (kvt-half w&1, s = 2*(w>>1)+i)
    // and V regions {2w, 2w+1}. All sources contiguous 1KB; LDS dest linear.
    const int kreg = (w & 1) * 8 + (w >> 1) * 2;   // K LDS region base
    const int loff = lane * 8;                     // slot offset (elements)

    float m_i = -INFINITY;   // running max, log2 domain (S * C2LOG)
    float l_i = 0.0f;
    f32x16 acc[4] = {};      // O^T: acc[dt], d = dt*32 + 8*(e>>2) + 4hi + (e&3), col q=l31

    // prologue: stage tile 0 (K and V) into par 0
    #pragma unroll
    for (int i = 0; i < 2; i++)
        GLD16(Kfb + (size_t)(w & 1) * 4096 + ((w >> 1) * 2 + i) * 512 + loff,
              &Ktd[(kreg + i) * 512 + loff]);
    #pragma unroll
    for (int i = 0; i < 2; i++)
        GLD16(Vfb + (2 * w + i) * 512 + loff, &Vsd[(2 * w + i) * 512 + loff]);
    // pin the qf waitcnt into the prologue (fake use)
    asm volatile("" :: "v"(qf[0]), "v"(qf[1]), "v"(qf[2]), "v"(qf[3]),
                       "v"(qf[4]), "v"(qf[5]), "v"(qf[6]), "v"(qf[7]));

    for (int kt = 0; kt < nbig; kt++) {
        const int kvb = kt * 64;
        const int par = kt & 1;
        const bool active = (kt < my_nt);

        asm volatile("s_waitcnt vmcnt(0)" ::: "memory");  // my tile-kt loads done
        __builtin_amdgcn_s_barrier();   // all tile-kt loads visible; par^1 free
        asm volatile("" ::: "memory");

        // ---- stage tile kt+1 into par^1 (clamped dup on last) ----
        {
            const int kt1 = (kt + 1 < nbig) ? kt + 1 : kt;
            const int pn = (par ^ 1) * 8192;
            const size_t ksrc = (size_t)(2 * kt1 + (w & 1)) * 4096 + (w >> 1) * 1024;
            #pragma unroll
            for (int i = 0; i < 2; i++)
                GLD16(Kfb + ksrc + i * 512 + loff,
                      &Ktd[pn + (kreg + i) * 512 + loff]);
            const size_t vsrc = (size_t)kt1 * 8192 + 2 * w * 512;
            #pragma unroll
            for (int i = 0; i < 2; i++)
                GLD16(Vfb + vsrc + i * 512 + loff,
                      &Vsd[pn + (2 * w + i) * 512 + loff]);
        }

        if (active) {
            const __hip_bfloat16* kb_base = &Ktd[par * 8192];
            const __hip_bfloat16* vb_base = &Vsd[par * 8192];

            // ---- S^T = K * Q^T : 2 kv-blocks x 8 k-steps of 32x32x16 ----
            f32x16 st[2] = {};
            __builtin_amdgcn_s_setprio(1);
            #pragma unroll
            for (int s = 0; s < 8; s++)
                #pragma unroll
                for (int kb = 0; kb < 2; kb++) {
                    bf16x8 kf = ld_frag(kb_base + (kb * 8 + s) * 512 + loff);
                    st[kb] = __builtin_amdgcn_mfma_f32_32x32x16_bf16(
                        kf, qf[s], st[kb], 0, 0, 0);
                }
            __builtin_amdgcn_s_setprio(0);

            // ---- row max; causal cndmask only on the diagonal tile ----
            float tmx = -INFINITY;
            if (kvb + 63 > qwb) {            // wave-uniform: diagonal tile
                const int thr = q - kvb - 4 * hi;   // pass iff kb*32 + 8g + r <= thr
                #pragma unroll
                for (int kb = 0; kb < 2; kb++)
                    #pragma unroll
                    for (int g = 0; g < 4; g++)
                        #pragma unroll
                        for (int r = 0; r < 4; r++) {
                            const int e = g * 4 + r;
                            float v = (kb * 32 + 8 * g + r <= thr) ? st[kb][e] : -INFINITY;
                            st[kb][e] = v;
                            tmx = fmaxf(tmx, v);
                        }
            } else {                          // interior: no masking needed
                #pragma unroll
                for (int kb = 0; kb < 2; kb++)
                    #pragma unroll
                    for (int e = 0; e < 16; e++)
                        tmx = fmaxf(tmx, st[kb][e]);
            }
            tmx = fmaxf(tmx, __shfl_xor(tmx, 32));
            const float m2x = tmx * C2LOG;

            // ---- online softmax (log2 domain) + T13 defer-max ----
            const bool nosc = __all(m2x <= m_i + 8.0f);
            const float mnew = nosc ? m_i : fmaxf(m_i, m2x);
            float rs = 0.0f;
            #pragma unroll
            for (int kb = 0; kb < 2; kb++)
                #pragma unroll
                for (int e = 0; e < 16; e++) {
                    float pv = exp2f(fmaf(st[kb][e], C2LOG, -mnew));
                    st[kb][e] = pv;
                    rs += pv;
                }
            rs += __shfl_xor(rs, 32);
            if (!nosc) {
                const float alpha = exp2f(m_i - mnew);
                m_i = mnew;
                l_i *= alpha;
                #pragma unroll
                for (int dt = 0; dt < 4; dt++)
                    #pragma unroll
                    for (int e = 0; e < 16; e++)
                        acc[dt][e] *= alpha;
            }
            l_i += rs;

            // ---- P -> bf16 PV B-frags entirely in registers (T12) ----
            uint4 af[4];
            #pragma unroll
            for (int kb = 0; kb < 2; kb++) {
                unsigned int pk[4][2];
                #pragma unroll
                for (int g = 0; g < 4; g++)
                    #pragma unroll
                    for (int i = 0; i < 2; i++) {
                        float2 fp = make_float2(st[kb][g * 4 + 2 * i],
                                                st[kb][g * 4 + 2 * i + 1]);
                        __hip_bfloat162 h2 = __float22bfloat162_rn(fp);
                        pk[g][i] = *reinterpret_cast<unsigned int*>(&h2);
                    }
                #pragma unroll
                for (int sl = 0; sl < 2; sl++) {
                    uintx2 r0 = __builtin_amdgcn_permlane32_swap(
                        pk[2 * sl][0], pk[2 * sl + 1][0], false, false);
                    uintx2 r1 = __builtin_amdgcn_permlane32_swap(
                        pk[2 * sl][1], pk[2 * sl + 1][1], false, false);
                    af[kb * 2 + sl] = make_uint4(r0[0], r1[0], r0[1], r1[1]);
                }
            }

            // ---- O^T += V^T * P^T : 4 d-tiles x 4 kv-steps ----
            __builtin_amdgcn_s_setprio(1);
            #pragma unroll
            for (int s = 0; s < 4; s++) {
                bf16x8 pf = __builtin_bit_cast(bf16x8, af[s]);
                #pragma unroll
                for (int dt = 0; dt < 4; dt++) {
                    bf16x8 vf = ld_frag(vb_base + (dt * 4 + s) * 512 + loff);
                    acc[dt] = __builtin_amdgcn_mfma_f32_32x32x16_bf16(
                        vf, pf, acc[dt], 0, 0, 0);
                }
            }
            __builtin_amdgcn_s_setprio(0);
        }
    }

    // ---- epilogue: per-lane q = l31, d = dt*32 + 8g + 4hi + r ----
    const float inv_l = 1.0f / l_i;
    __hip_bfloat16* orow = O + (size_t)(b * SS + q) * 2048 + h * 128;
    #pragma unroll
    for (int dt = 0; dt < 4; dt++)
        #pragma unroll
        for (int g = 0; g < 4; g++) {
            ushort u[4];
            #pragma unroll
            for (int r = 0; r < 4; r++)
                u[r] = bf_bits(acc[dt][g * 4 + r] * inv_l);
            *reinterpret_cast<uint2*>(orow + dt * 32 + 8 * g + 4 * hi) =
                *reinterpret_cast<uint2*>(u);
        }
}

// ---------------------------------------------------------------------------
extern "C" void kernel_launch(void* const* d_in, const int* in_sizes, int n_in,
                              void* d_out, int out_size, void* d_ws, size_t ws_size,
                              hipStream_t stream)
{
    const float* hs       = (const float*)d_in[0];
    const float* w_kv_d   = (const float*)d_in[1];
    const float* w_q_d    = (const float*)d_in[2];
    const float* w_k_u    = (const float*)d_in[3];
    const float* w_q_u    = (const float*)d_in[4];
    const float* w_v_u    = (const float*)d_in[5];
    const float* w_rope_k = (const float*)d_in[6];
    const float* w_rope_q = (const float*)d_in[7];
    const float* w_o      = (const float*)d_in[8];
    float* out = (float*)d_out;

    char* p = (char*)d_ws;
    auto alloc = [&](size_t nelem) {
        __hip_bfloat16* r = (__hip_bfloat16*)p;
        p += nelem * sizeof(__hip_bfloat16);
        return r;
    };
    __hip_bfloat16* hsb  = alloc((size_t)BS * HID);        // 16 MB (reused as attn)
    __hip_bfloat16* qkvd = alloc((size_t)BS * 512);        // 4 MB
    __hip_bfloat16* WT1  = alloc((size_t)1536 * 2048);     // 6 MB
    __hip_bfloat16* WT2  = alloc((size_t)3072 * 256);      // 1.5 MB
    __hip_bfloat16* WT3  = alloc((size_t)2048 * 256);      // 1 MB
    __hip_bfloat16* WTo  = alloc((size_t)2048 * 2048);     // 8 MB
    __hip_bfloat16* Kf   = alloc((size_t)BS * HID);        // 16 MB, fragment-order K
    __hip_bfloat16* Qbuf = alloc((size_t)BS * HID);        // 16 MB
    __hip_bfloat16* Vf   = alloc((size_t)HID * BS);        // 16 MB, fragment-order V
    __hip_bfloat16* attn = hsb;   // hs dead after G1

    dim3 blk(256);

    // 0a. hs -> bf16
    convert_kernel<<<dim3((BS * HID / 8 + 255) / 256), blk, 0, stream>>>(
        hs, hsb, BS * HID / 8);
    // 0b. all weights: transpose + convert to bf16 W^T
    transpose_weights_kernel<<<dim3(8448), blk, 0, stream>>>(
        w_kv_d, w_q_d, w_rope_k, w_k_u, w_v_u, w_q_u, w_rope_q, w_o,
        WT1, WT2, WT3, WTo);

    // G1: [kv_d | q_d | krp] = hsb @ WT1^T  (N=1536, K=2048); krp -> Kf d=64..127
    gemm_bt_kernel<__hip_bfloat16><<<dim3(1536 / 128, BS / 128), blk, 0, stream>>>(
        hsb, 2048, WT1,
        qkvd, 512, 0, 0, 1.0f,
        Kf, 0, 3, 64, 1.0f,
        512, 2048);
    // G2: [k_p | v] = kv_d @ WT2^T  (N=3072, K=256); k_p -> Kf d=0..63, v -> Vf
    gemm_bt_kernel<__hip_bfloat16><<<dim3(3072 / 128, BS / 128), blk, 0, stream>>>(
        qkvd, 512, WT2,
        Kf, 0, 3, 0, 1.0f,
        Vf, 0, 4, 0, 1.0f,
        1024, 256);
    // G3: [q_p | q_rope_pre] = q_d @ WT3^T  (N=2048, K=256)
    gemm_bt_kernel<__hip_bfloat16><<<dim3(2048 / 128, BS / 128), blk, 0, stream>>>(
        qkvd + 256, 512, WT3,
        Qbuf, 2048, 1, 0, 1.0f,
        Qbuf, 2048, 1, 64, 1.0f,
        1024, 256);
    // 4. RoPE in-place (K in Kf layout, Q row-major)
    rope_kernel<<<dim3((BS * NH * 32 + 255) / 256), blk, 0, stream>>>(Kf, Qbuf);
    // 5. flash attention v13 -> attn (fragment-order global K/V, 1 barrier/iter)
    flash_attn_kernel<<<dim3(8, NH, BB), dim3(512), 0, stream>>>(
        Qbuf, Kf, Vf, attn);
    // G4: out = attn @ WTo^T (fp32 out)
    gemm_bt_kernel<float><<<dim3(2048 / 128, BS / 128), blk, 0, stream>>>(
        attn, 2048, WTo,
        out, 2048, 0, 0, 1.0f,
        out, 2048, 0, 0, 1.0f,
        2048, 2048);
}

// Round 7
// 336.535 us; speedup vs baseline: 1.0438x; 1.0269x over previous
//
#include <hip/hip_runtime.h>
#include <hip/hip_bf16.h>

// Problem constants: B=2, S=2048, HID=2048, H=16, HD=128, HD2=64, LAT=256
#define BB 2
#define SS 2048
#define HID 2048
#define NH 16
#define BS (BB*SS)          // 4096 rows
#define SCALE 0.088388347648318447f   // 1/sqrt(128)
#define C2LOG 0.12751743f              // SCALE * log2(e)

typedef __bf16 bf16x8 __attribute__((ext_vector_type(8)));
typedef float f32x4 __attribute__((ext_vector_type(4)));
typedef float f32x16 __attribute__((ext_vector_type(16)));
typedef unsigned int uintx2 __attribute__((ext_vector_type(2)));

__device__ __forceinline__ bf16x8 ld_frag(const __hip_bfloat16* p) {
    uint4 u = *reinterpret_cast<const uint4*>(p);
    return __builtin_bit_cast(bf16x8, u);
}
// HW packed f32->bf16 convert (RNE). gfx950 has no builtin (m240): inline asm.
// Replaces the ~10-inst software RN in __float2bfloat16 (r6: ~1000 hidden VALU
// cyc/wave-tile in flash; ~10% of GEMM time in epilogues).
__device__ __forceinline__ unsigned int cvt_pk_bf16(float a, float b) {
    unsigned int r;
    asm("v_cvt_pk_bf16_f32 %0, %1, %2" : "=v"(r) : "v"(a), "v"(b));
    return r;
}
__device__ __forceinline__ ushort bf_bits(float v) {
    return (ushort)cvt_pk_bf16(v, v);
}
__device__ __forceinline__ void store_c(__hip_bfloat16* C, size_t idx, float v) {
    *reinterpret_cast<ushort*>(&C[idx]) = bf_bits(v);
}
__device__ __forceinline__ void store_c(float* C, size_t idx, float v) {
    C[idx] = v;
}

// async global->LDS, 16B per lane; lds addr must be wave-uniform base + lane*16
#define GLD16(gp, lp) \
  __builtin_amdgcn_global_load_lds((const __attribute__((address_space(1))) void*)(gp), \
                                   (__attribute__((address_space(3))) void*)(lp), 16, 0, 0)

// ---------------------------------------------------------------------------
// Fragment-order global layouts (v13, kept).
// Kf: element K[b][kv][h][d] ->
//   (b*16+h)*262144 + (kv>>5)*4096 + (d>>4)*512 + ((d>>3)&1)*256 + (kv&31)*8 + (d&7)
// Vf: element V[b][kv][h][d] ->
//   (b*16+h)*262144 + (kv>>6)*8192 + (d>>5)*2048 + ((kv>>4)&3)*512
//   + ((kv>>3)&1)*256 + (d&31)*8 + (kv&7)
// ---------------------------------------------------------------------------

// ---------------------------------------------------------------------------
// fp32 -> bf16 flat convert (hs)
// ---------------------------------------------------------------------------
__global__ __launch_bounds__(256) void convert_kernel(
    const float* __restrict__ src, __hip_bfloat16* __restrict__ dst, int n8)
{
    int i = blockIdx.x * blockDim.x + threadIdx.x;
    if (i >= n8) return;
    float4 a = reinterpret_cast<const float4*>(src)[2 * i];
    float4 b = reinterpret_cast<const float4*>(src)[2 * i + 1];
    uint4 o;
    o.x = cvt_pk_bf16(a.x, a.y);
    o.y = cvt_pk_bf16(a.z, a.w);
    o.z = cvt_pk_bf16(b.x, b.y);
    o.w = cvt_pk_bf16(b.z, b.w);
    reinterpret_cast<uint4*>(dst)[i] = o;
}

// ---------------------------------------------------------------------------
// Fused weight transpose+convert: 8 segments, src fp32 [R][C] -> dst bf16 [C][R]
// ---------------------------------------------------------------------------
__global__ __launch_bounds__(256) void transpose_weights_kernel(
    const float* s0, const float* s1, const float* s2, const float* s3,
    const float* s4, const float* s5, const float* s6, const float* s7,
    __hip_bfloat16* WT1, __hip_bfloat16* WT2, __hip_bfloat16* WT3,
    __hip_bfloat16* WTo)
{
    const float* srcs[8] = { s0, s1, s2, s3, s4, s5, s6, s7 };
    const int Rs[8] = { 2048, 2048, 2048, 256, 256, 256, 256, 2048 };
    const int Cs[8] = { 256, 256, 1024, 1024, 2048, 1024, 1024, 2048 };
    __hip_bfloat16* dsts[8] = {
        WT1, WT1 + (size_t)256 * 2048, WT1 + (size_t)512 * 2048,
        WT2, WT2 + (size_t)1024 * 256,
        WT3, WT3 + (size_t)1024 * 256,
        WTo };
    const int prefix[9] = { 0, 512, 1024, 3072, 3328, 3840, 4096, 4352, 8448 };

    int bid = blockIdx.x;
    int seg = 0;
    #pragma unroll
    for (int i = 0; i < 8; i++) if (bid >= prefix[i + 1]) seg = i + 1;
    int local = bid - prefix[seg];
    int R = Rs[seg], C = Cs[seg];
    int tilesC = C / 32;
    int tr = local / tilesC, tc = local % tilesC;
    int r0 = tr * 32, c0 = tc * 32;
    const float* src = srcs[seg];
    __hip_bfloat16* dst = dsts[seg];

    __shared__ float Ts[32][33];
    int t = threadIdx.x;
    int ty = t >> 5, tx = t & 31;
    #pragma unroll
    for (int k = 0; k < 4; k++) {
        int r = ty + k * 8;
        Ts[r][tx] = src[(size_t)(r0 + r) * C + c0 + tx];
    }
    __syncthreads();
    #pragma unroll
    for (int k = 0; k < 4; k++) {
        int r = ty + k * 8;
        *reinterpret_cast<ushort*>(&dst[(size_t)(c0 + r) * R + r0 + tx]) =
            bf_bits(Ts[tx][r]);
    }
}

// ---------------------------------------------------------------------------
// m97-style GEMM: C = A[M,K] * Bt[N,K]^T, bf16 in, fp32 acc.
// 128x128 tile, BK=32, global_load_lds staging, 4 waves each 64x64.
// + bijective XCD swizzle (T1; all grids here have nwg%8==0).
// Epilogue routing: col < splitN -> (C0,...) else (C1,...). cm = output scale.
//   s64==0: plain col
//   s64==1: col c -> (c>>6)*128 + (c&63) + off (head scatter, row-major)
//   s64==2: transposed store: Cp[c*4096 + row]
//   s64==3: Kf fragment-order scatter; c: h=c>>6, d=off+(c&63); row m: b,kv
//   s64==4: Vf fragment-order scatter; c: h=c>>7, d=c&127;    row m: b,kv
// ---------------------------------------------------------------------------
template <typename TC>
__global__ __launch_bounds__(256) void gemm_bt_kernel(
    const __hip_bfloat16* __restrict__ A, int lda,
    const __hip_bfloat16* __restrict__ Bt,
    TC* __restrict__ C0, int ldc0, int sp0, int off0, float cm0,
    TC* __restrict__ C1, int ldc1, int sp1, int off1, float cm1,
    int splitN, int K)
{
    __shared__ alignas(16) __hip_bfloat16 As[128 * 32];
    __shared__ alignas(16) __hip_bfloat16 Bs[128 * 32];

    // XCD-aware bijective remap (nwg % 8 == 0 for all launches here)
    const int nwg = gridDim.x * gridDim.y;
    int lin = blockIdx.y * gridDim.x + blockIdx.x;
    lin = (lin & 7) * (nwg >> 3) + (lin >> 3);
    const int bn = (lin % gridDim.x) * 128;
    const int bm = (lin / gridDim.x) * 128;

    const int t = threadIdx.x;
    const int w = t >> 6;
    const int lane = t & 63;
    const int l15 = lane & 15;
    const int quad = lane >> 4;
    const int wm = (w & 1) * 64;
    const int wn = (w >> 1) * 64;

    const int srow = lane >> 2;          // 0..15
    const int skcol = (lane & 3) * 8;    // 0,8,16,24

    f32x4 acc[4][4] = {};

    for (int k0 = 0; k0 < K; k0 += 32) {
        __syncthreads();
        #pragma unroll
        for (int i = 0; i < 2; i++) {
            int r = w * 32 + i * 16 + srow;
            GLD16(A + (size_t)(bm + r) * lda + k0 + skcol, &As[r * 32 + skcol]);
            GLD16(Bt + (size_t)(bn + r) * K + k0 + skcol, &Bs[r * 32 + skcol]);
        }
        __syncthreads();

        bf16x8 af[4], bf[4];
        #pragma unroll
        for (int mt = 0; mt < 4; mt++)
            af[mt] = ld_frag(&As[(wm + mt * 16 + l15) * 32 + quad * 8]);
        #pragma unroll
        for (int nt = 0; nt < 4; nt++)
            bf[nt] = ld_frag(&Bs[(wn + nt * 16 + l15) * 32 + quad * 8]);
        #pragma unroll
        for (int mt = 0; mt < 4; mt++)
            #pragma unroll
            for (int nt = 0; nt < 4; nt++)
                acc[mt][nt] = __builtin_amdgcn_mfma_f32_16x16x32_bf16(
                    af[mt], bf[nt], acc[mt][nt], 0, 0, 0);
    }

    #pragma unroll
    for (int nt = 0; nt < 4; nt++) {
        int col = bn + wn + nt * 16 + l15;
        TC* Cp; int c, ld, s64, off; float cm;
        if (col < splitN) { Cp = C0; c = col; ld = ldc0; s64 = sp0; off = off0; cm = cm0; }
        else { Cp = C1; c = col - splitN; ld = ldc1; s64 = sp1; off = off1; cm = cm1; }
        if (s64 == 2) {
            #pragma unroll
            for (int mt = 0; mt < 4; mt++) {
                int row0 = bm + wm + mt * 16 + quad * 4;
                #pragma unroll
                for (int r = 0; r < 4; r++)
                    store_c(Cp, (size_t)c * 4096 + row0 + r, acc[mt][nt][r] * cm);
            }
        } else if (s64 == 3) {
            const int hh = c >> 6, d = off + (c & 63);
            const size_t dbase = (size_t)(d >> 4) * 512
                               + (size_t)((d >> 3) & 1) * 256 + (d & 7);
            #pragma unroll
            for (int mt = 0; mt < 4; mt++) {
                #pragma unroll
                for (int r = 0; r < 4; r++) {
                    int m = bm + wm + mt * 16 + quad * 4 + r;
                    int bb2 = m >> 11, kv = m & 2047;
                    size_t idx = (size_t)(bb2 * 16 + hh) * 262144
                               + (size_t)(kv >> 5) * 4096 + dbase
                               + (size_t)(kv & 31) * 8;
                    store_c(Cp, idx, acc[mt][nt][r] * cm);
                }
            }
        } else if (s64 == 4) {
            const int hh = c >> 7, d = c & 127;
            const size_t dbase = (size_t)(d >> 5) * 2048 + (size_t)(d & 31) * 8;
            #pragma unroll
            for (int mt = 0; mt < 4; mt++) {
                #pragma unroll
                for (int r = 0; r < 4; r++) {
                    int m = bm + wm + mt * 16 + quad * 4 + r;
                    int bb2 = m >> 11, kv = m & 2047;
                    size_t idx = (size_t)(bb2 * 16 + hh) * 262144
                               + (size_t)(kv >> 6) * 8192 + dbase
                               + (size_t)((kv >> 4) & 3) * 512
                               + (size_t)((kv >> 3) & 1) * 256 + (kv & 7);
                    store_c(Cp, idx, acc[mt][nt][r] * cm);
                }
            }
        } else {
            int oc = s64 ? ((c >> 6) * 128 + (c & 63) + off) : c;
            #pragma unroll
            for (int mt = 0; mt < 4; mt++) {
                #pragma unroll
                for (int r = 0; r < 4; r++) {
                    int row = bm + wm + mt * 16 + quad * 4 + r;
                    store_c(Cp, (size_t)row * ld + oc, acc[mt][nt][r] * cm);
                }
            }
        }
    }
}

// ---------------------------------------------------------------------------
// RoPE in-place: K in Kf fragment-order layout, Q in row-major Qbuf.
// Pair (d1=64+i, d2=96+i): in Kf, d2 is exactly +2 regions = +1024 elems.
// ---------------------------------------------------------------------------
__global__ __launch_bounds__(256) void rope_kernel(
    __hip_bfloat16* __restrict__ Kf, __hip_bfloat16* __restrict__ Qb)
{
    int idx = blockIdx.x * blockDim.x + threadIdx.x;
    if (idx >= BS * NH * 32) return;
    int i = idx & 31;
    int h = (idx >> 5) & 15;
    int row = idx >> 9;
    int s = row & (SS - 1);
    int b = row >> 11;

    float inv = exp2f(-(float)i * 0.4152410118609203f);  // 10000^(-i/32)
    float ang = (float)s * inv;
    float sn = sinf(ang), cs = cosf(ang);

    {   // K (Kf layout)
        size_t kaddr = ((size_t)(b * 16 + h) * 64 + (s >> 5)) * 4096
                     + (size_t)(4 + (i >> 4)) * 512
                     + (size_t)(((i >> 3) & 1) * 32 + (s & 31)) * 8 + (i & 7);
        float x1 = __bfloat162float(Kf[kaddr]);
        float x2 = __bfloat162float(Kf[kaddr + 1024]);
        *reinterpret_cast<ushort*>(&Kf[kaddr])        = bf_bits(x1 * cs - x2 * sn);
        *reinterpret_cast<ushort*>(&Kf[kaddr + 1024]) = bf_bits(x1 * sn + x2 * cs);
    }
    {   // Q (row-major)
        size_t obase = (size_t)row * 2048 + h * 128 + 64 + i;
        float x1 = __bfloat162float(Qb[obase]);
        float x2 = __bfloat162float(Qb[obase + 32]);
        *reinterpret_cast<ushort*>(&Qb[obase])      = bf_bits(x1 * cs - x2 * sn);
        *reinterpret_cast<ushort*>(&Qb[obase + 32]) = bf_bits(x1 * sn + x2 * cs);
    }
}

// ---------------------------------------------------------------------------
// Flash attention v14 = v13 structure (proven: conflicts 0, FETCH 110MB) +
// VALU surgery. r6 counter-close: 1926 VALU cyc/wave-tile measured vs ~550
// modeled -> the gap was software bf16 rounding (__float22bfloat162_rn,
// ~10-12 insts/conversion x16/tile) + per-iter 64-bit staging address builds.
// v14: (1) v_cvt_pk_bf16_f32 inline asm for P-pack + epilogue (T12/m240);
// (2) staging via running pointers kp/vp += 8192/iter, fixed per-parity LDS
// dests; (3) max3-fusible fmax tree on the interior row-max.
// ---------------------------------------------------------------------------
__global__ __launch_bounds__(512) void flash_attn_kernel(
    const __hip_bfloat16* __restrict__ Q,
    const __hip_bfloat16* __restrict__ Kf,
    const __hip_bfloat16* __restrict__ Vf,
    __hip_bfloat16* __restrict__ O)
{
    __shared__ alignas(16) __hip_bfloat16 Ktd[2 * 16 * 512];  // [par][region kb*8+s][slot]
    __shared__ alignas(16) __hip_bfloat16 Vsd[2 * 16 * 512];  // [par][region dt*4+sr][slot]

    const int p = blockIdx.x;            // pair index 0..7
    const int h = blockIdx.y;
    const int b = blockIdx.z;
    const int t = threadIdx.x;
    const int w = t >> 6;                // 0..7
    const int lane = t & 63;
    const int l31 = lane & 31;
    const int hi = lane >> 5;

    const int qt = (w < 4) ? (15 - p) : p;   // this wave's q-tile
    const int wq = w & 3;
    const int qwb = qt * 128 + wq * 32;      // wave's q base (32 rows)
    const int q = qwb + l31;                 // this lane's q row
    const int my_nt = 2 * qt + 1 + (wq >> 1);// kv tiles this wave needs
    const int nbig = 2 * (15 - p) + 2;       // shared loop length

    const __hip_bfloat16* Kfb = Kf + (size_t)(b * 16 + h) * 262144;
    const __hip_bfloat16* Vfb = Vf + (size_t)(b * 16 + h) * 262144;

    // Q B-frags: qf[s] = Q[q][d = 16s + 8hi + j], j=0..7
    bf16x8 qf[8];
    {
        const __hip_bfloat16* qrow = Q + (size_t)(b * SS + q) * 2048 + h * 128;
        #pragma unroll
        for (int s = 0; s < 8; s++)
            qf[s] = ld_frag(qrow + s * 16 + hi * 8);
    }

    // staging: wave w stages K regions (kvt-half w&1, s = 2*(w>>1)+i) and V
    // regions {2w, 2w+1}. Running global pointers advance +8192 elems/tile.
    const int kreg = (w & 1) * 8 + (w >> 1) * 2;   // K LDS region base
    const int loff = lane * 8;                     // slot offset (elements)
    const __hip_bfloat16* kp = Kfb + (size_t)((w & 1) * 4096 + (w >> 1) * 1024) + loff;
    const __hip_bfloat16* vp = Vfb + (size_t)(2 * w) * 512 + loff;
    __hip_bfloat16* kd[2] = { &Ktd[kreg * 512 + loff], &Ktd[8192 + kreg * 512 + loff] };
    __hip_bfloat16* vd[2] = { &Vsd[2 * w * 512 + loff], &Vsd[8192 + 2 * w * 512 + loff] };

    float m_i = -INFINITY;   // running max, log2 domain (S * C2LOG)
    float l_i = 0.0f;
    f32x16 acc[4] = {};      // O^T: acc[dt], d = dt*32 + 8*(e>>2) + 4hi + (e&3), col q=l31

    // prologue: stage tile 0 (K and V) into par 0
    GLD16(kp, kd[0]);
    GLD16(kp + 512, kd[0] + 512);
    GLD16(vp, vd[0]);
    GLD16(vp + 512, vd[0] + 512);
    kp += 8192; vp += 8192;
    // pin the qf waitcnt into the prologue (fake use)
    asm volatile("" :: "v"(qf[0]), "v"(qf[1]), "v"(qf[2]), "v"(qf[3]),
                       "v"(qf[4]), "v"(qf[5]), "v"(qf[6]), "v"(qf[7]));

    for (int kt = 0; kt < nbig; kt++) {
        const int kvb = kt * 64;
        const int par = kt & 1;
        const bool active = (kt < my_nt);

        asm volatile("s_waitcnt vmcnt(0)" ::: "memory");  // my tile-kt loads done
        __builtin_amdgcn_s_barrier();   // all tile-kt loads visible; par^1 free
        asm volatile("" ::: "memory");

        // ---- stage tile kt+1 into par^1 (pointer held on last tiles) ----
        {
            const int pn = par ^ 1;
            GLD16(kp, kd[pn]);
            GLD16(kp + 512, kd[pn] + 512);
            GLD16(vp, vd[pn]);
            GLD16(vp + 512, vd[pn] + 512);
            if (kt + 2 < nbig) { kp += 8192; vp += 8192; }
        }

        if (active) {
            const __hip_bfloat16* kb_base = &Ktd[par * 8192];
            const __hip_bfloat16* vb_base = &Vsd[par * 8192];

            // ---- S^T = K * Q^T : 2 kv-blocks x 8 k-steps of 32x32x16 ----
            f32x16 st[2] = {};
            __builtin_amdgcn_s_setprio(1);
            #pragma unroll
            for (int s = 0; s < 8; s++)
                #pragma unroll
                for (int kb = 0; kb < 2; kb++) {
                    bf16x8 kf = ld_frag(kb_base + (kb * 8 + s) * 512 + loff);
                    st[kb] = __builtin_amdgcn_mfma_f32_32x32x16_bf16(
                        kf, qf[s], st[kb], 0, 0, 0);
                }
            __builtin_amdgcn_s_setprio(0);

            // ---- row max; causal cndmask only on the diagonal tile ----
            float tmx;
            if (kvb + 63 > qwb) {            // wave-uniform: diagonal tile
                const int thr = q - kvb - 4 * hi;   // pass iff kb*32 + 8g + r <= thr
                tmx = -INFINITY;
                #pragma unroll
                for (int kb = 0; kb < 2; kb++)
                    #pragma unroll
                    for (int g = 0; g < 4; g++)
                        #pragma unroll
                        for (int r = 0; r < 4; r++) {
                            const int e = g * 4 + r;
                            float v = (kb * 32 + 8 * g + r <= thr) ? st[kb][e] : -INFINITY;
                            st[kb][e] = v;
                            tmx = fmaxf(tmx, v);
                        }
            } else {                          // interior: max3-fusible tree
                tmx = fmaxf(st[0][0], st[0][1]);
                #pragma unroll
                for (int e = 2; e < 16; e += 2)
                    tmx = fmaxf(fmaxf(tmx, st[0][e]), st[0][e + 1]);
                #pragma unroll
                for (int e = 0; e < 16; e += 2)
                    tmx = fmaxf(fmaxf(tmx, st[1][e]), st[1][e + 1]);
            }
            tmx = fmaxf(tmx, __shfl_xor(tmx, 32));
            const float m2x = tmx * C2LOG;

            // ---- online softmax (log2 domain) + T13 defer-max ----
            const bool nosc = __all(m2x <= m_i + 8.0f);
            const float mnew = nosc ? m_i : fmaxf(m_i, m2x);
            float rs = 0.0f;
            #pragma unroll
            for (int kb = 0; kb < 2; kb++)
                #pragma unroll
                for (int e = 0; e < 16; e++) {
                    float pv = exp2f(fmaf(st[kb][e], C2LOG, -mnew));
                    st[kb][e] = pv;
                    rs += pv;
                }
            rs += __shfl_xor(rs, 32);
            if (!nosc) {
                const float alpha = exp2f(m_i - mnew);
                m_i = mnew;
                l_i *= alpha;
                #pragma unroll
                for (int dt = 0; dt < 4; dt++)
                    #pragma unroll
                    for (int e = 0; e < 16; e++)
                        acc[dt][e] *= alpha;
            }
            l_i += rs;

            // ---- P -> bf16 PV B-frags in registers (T12, HW cvt_pk) ----
            uint4 af[4];
            #pragma unroll
            for (int kb = 0; kb < 2; kb++) {
                unsigned int pk[4][2];
                #pragma unroll
                for (int g = 0; g < 4; g++)
                    #pragma unroll
                    for (int i = 0; i < 2; i++)
                        pk[g][i] = cvt_pk_bf16(st[kb][g * 4 + 2 * i],
                                               st[kb][g * 4 + 2 * i + 1]);
                #pragma unroll
                for (int sl = 0; sl < 2; sl++) {
                    uintx2 r0 = __builtin_amdgcn_permlane32_swap(
                        pk[2 * sl][0], pk[2 * sl + 1][0], false, false);
                    uintx2 r1 = __builtin_amdgcn_permlane32_swap(
                        pk[2 * sl][1], pk[2 * sl + 1][1], false, false);
                    af[kb * 2 + sl] = make_uint4(r0[0], r1[0], r0[1], r1[1]);
                }
            }

            // ---- O^T += V^T * P^T : 4 d-tiles x 4 kv-steps ----
            __builtin_amdgcn_s_setprio(1);
            #pragma unroll
            for (int s = 0; s < 4; s++) {
                bf16x8 pf = __builtin_bit_cast(bf16x8, af[s]);
                #pragma unroll
                for (int dt = 0; dt < 4; dt++) {
                    bf16x8 vf = ld_frag(vb_base + (dt * 4 + s) * 512 + loff);
                    acc[dt] = __builtin_amdgcn_mfma_f32_32x32x16_bf16(
                        vf, pf, acc[dt], 0, 0, 0);
                }
            }
            __builtin_amdgcn_s_setprio(0);
        }
    }

    // ---- epilogue: per-lane q = l31, d = dt*32 + 8g + 4hi + r ----
    const float inv_l = 1.0f / l_i;
    __hip_bfloat16* orow = O + (size_t)(b * SS + q) * 2048 + h * 128;
    #pragma unroll
    for (int dt = 0; dt < 4; dt++)
        #pragma unroll
        for (int g = 0; g < 4; g++) {
            uint2 uu;
            uu.x = cvt_pk_bf16(acc[dt][g * 4 + 0] * inv_l, acc[dt][g * 4 + 1] * inv_l);
            uu.y = cvt_pk_bf16(acc[dt][g * 4 + 2] * inv_l, acc[dt][g * 4 + 3] * inv_l);
            *reinterpret_cast<uint2*>(orow + dt * 32 + 8 * g + 4 * hi) = uu;
        }
}

// ---------------------------------------------------------------------------
extern "C" void kernel_launch(void* const* d_in, const int* in_sizes, int n_in,
                              void* d_out, int out_size, void* d_ws, size_t ws_size,
                              hipStream_t stream)
{
    const float* hs       = (const float*)d_in[0];
    const float* w_kv_d   = (const float*)d_in[1];
    const float* w_q_d    = (const float*)d_in[2];
    const float* w_k_u    = (const float*)d_in[3];
    const float* w_q_u    = (const float*)d_in[4];
    const float* w_v_u    = (const float*)d_in[5];
    const float* w_rope_k = (const float*)d_in[6];
    const float* w_rope_q = (const float*)d_in[7];
    const float* w_o      = (const float*)d_in[8];
    float* out = (float*)d_out;

    char* p = (char*)d_ws;
    auto alloc = [&](size_t nelem) {
        __hip_bfloat16* r = (__hip_bfloat16*)p;
        p += nelem * sizeof(__hip_bfloat16);
        return r;
    };
    __hip_bfloat16* hsb  = alloc((size_t)BS * HID);        // 16 MB (reused as attn)
    __hip_bfloat16* qkvd = alloc((size_t)BS * 512);        // 4 MB
    __hip_bfloat16* WT1  = alloc((size_t)1536 * 2048);     // 6 MB
    __hip_bfloat16* WT2  = alloc((size_t)3072 * 256);      // 1.5 MB
    __hip_bfloat16* WT3  = alloc((size_t)2048 * 256);      // 1 MB
    __hip_bfloat16* WTo  = alloc((size_t)2048 * 2048);     // 8 MB
    __hip_bfloat16* Kf   = alloc((size_t)BS * HID);        // 16 MB, fragment-order K
    __hip_bfloat16* Qbuf = alloc((size_t)BS * HID);        // 16 MB
    __hip_bfloat16* Vf   = alloc((size_t)HID * BS);        // 16 MB, fragment-order V
    __hip_bfloat16* attn = hsb;   // hs dead after G1

    dim3 blk(256);

    // 0a. hs -> bf16
    convert_kernel<<<dim3((BS * HID / 8 + 255) / 256), blk, 0, stream>>>(
        hs, hsb, BS * HID / 8);
    // 0b. all weights: transpose + convert to bf16 W^T
    transpose_weights_kernel<<<dim3(8448), blk, 0, stream>>>(
        w_kv_d, w_q_d, w_rope_k, w_k_u, w_v_u, w_q_u, w_rope_q, w_o,
        WT1, WT2, WT3, WTo);

    // G1: [kv_d | q_d | krp] = hsb @ WT1^T  (N=1536, K=2048); krp -> Kf d=64..127
    gemm_bt_kernel<__hip_bfloat16><<<dim3(1536 / 128, BS / 128), blk, 0, stream>>>(
        hsb, 2048, WT1,
        qkvd, 512, 0, 0, 1.0f,
        Kf, 0, 3, 64, 1.0f,
        512, 2048);
    // G2: [k_p | v] = kv_d @ WT2^T  (N=3072, K=256); k_p -> Kf d=0..63, v -> Vf
    gemm_bt_kernel<__hip_bfloat16><<<dim3(3072 / 128, BS / 128), blk, 0, stream>>>(
        qkvd, 512, WT2,
        Kf, 0, 3, 0, 1.0f,
        Vf, 0, 4, 0, 1.0f,
        1024, 256);
    // G3: [q_p | q_rope_pre] = q_d @ WT3^T  (N=2048, K=256)
    gemm_bt_kernel<__hip_bfloat16><<<dim3(2048 / 128, BS / 128), blk, 0, stream>>>(
        qkvd + 256, 512, WT3,
        Qbuf, 2048, 1, 0, 1.0f,
        Qbuf, 2048, 1, 64, 1.0f,
        1024, 256);
    // 4. RoPE in-place (K in Kf layout, Q row-major)
    rope_kernel<<<dim3((BS * NH * 32 + 255) / 256), blk, 0, stream>>>(Kf, Qbuf);
    // 5. flash attention v14 -> attn
    flash_attn_kernel<<<dim3(8, NH, BB), dim3(512), 0, stream>>>(
        Qbuf, Kf, Vf, attn);
    // G4: out = attn @ WTo^T (fp32 out)
    gemm_bt_kernel<float><<<dim3(2048 / 128, BS / 128), blk, 0, stream>>>(
        attn, 2048, WTo,
        out, 2048, 0, 0, 1.0f,
        out, 2048, 0, 0, 1.0f,
        2048, 2048);
}